// Round 4
// baseline (56.178 us; speedup 1.0000x reference)
//
#include <hip/hip_runtime.h>
#include <hip/hip_bf16.h>

typedef float f32x4 __attribute__((ext_vector_type(4)));
typedef long  l2    __attribute__((ext_vector_type(2)));

// ---------------------------------------------------------------------------
// async global->LDS, 16B per lane. LDS dest is wave-uniform base (+lane*16).
// ---------------------------------------------------------------------------
__device__ __forceinline__ void gld16(const void* g, void* l) {
    __builtin_amdgcn_global_load_lds(
        (const __attribute__((address_space(1))) void*)g,
        (__attribute__((address_space(3))) void*)l,
        16, 0, 0);
}

// gelu, tanh approximation (matches jax.nn.gelu approximate=True)
__device__ __forceinline__ float gelu_tanh(float x) {
    float u = 0.7978845608028654f * x * (1.0f + 0.044715f * x * x);
    float e = __expf(2.0f * u);
    float t = 1.0f - 2.0f / (e + 1.0f);   // tanh(u)
    return 0.5f * x * (1.0f + t);
}

// ---------------------------------------------------------------------------
// Pre-permuted fp8 storage layout (both A[M][K] and BT[N][K]):
// within each row's 64B k-segment:
//   step 1 (pair ks-halves): chunk g (16B) = orig k-bytes [g*8,+8) ++ [32+g*8,+8)
//   step 2 (bank swizzle):   stored at chunk position c = g ^ ((row>>1)&3)
// GEMM reads one ds_read_b128 per fragment-pair (lo 8B = ks0, hi = ks1),
// conflict-free across the wave. (Verified round 3: SQ_LDS_BANK_CONFLICT = 0.)
// ---------------------------------------------------------------------------

// Kernel 1: quantize x (f32 [M][K]) -> fp8 e4m3, permuted layout
__global__ __launch_bounds__(256) void quantA_kernel(
        const float* __restrict__ in, unsigned char* __restrict__ out,
        int n4, int K) {
    int i = blockIdx.x * 256 + threadIdx.x;
    if (i >= n4) return;
    float4 v = reinterpret_cast<const float4*>(in)[i];
    int pk = 0;
    pk = __builtin_amdgcn_cvt_pk_fp8_f32(v.x, v.y, pk, false);
    pk = __builtin_amdgcn_cvt_pk_fp8_f32(v.z, v.w, pk, true);
    const long k4 = (long)i * 4;
    const int  row = (int)(k4 / K);
    const int  k   = (int)(k4 % K);
    const int  o   = k & 63;
    const int  g   = (o & 31) >> 3;
    const int  s   = (o & 7) + ((o >> 5) & 1) * 8;
    const int  c   = g ^ ((row >> 1) & 3);
    *reinterpret_cast<unsigned int*>(
        out + (long)row * K + (k & ~63) + (c << 4) + s) = (unsigned int)pk;
}

// Kernel 2: quantize + transpose kernel (f32 [K][N]) -> fp8 BT[N][K], permuted
__global__ __launch_bounds__(256) void quantBT_kernel(
        const float* __restrict__ B, unsigned char* __restrict__ BT,
        int K, int N) {
    __shared__ unsigned char lds[64 * 68];    // [k=64][n=64], row stride 68 (pad)
    const int tid = threadIdx.x;
    const int n0 = blockIdx.x * 64;
    const int k0 = blockIdx.y * 64;

    #pragma unroll
    for (int p = 0; p < 4; ++p) {
        int s = p * 256 + tid;
        int r = s >> 4;          // k within tile (0..63)
        int c = s & 15;          // float4 group (covers n = 4c..4c+3)
        float4 v = *reinterpret_cast<const float4*>(
            B + (long)(k0 + r) * N + n0 + c * 4);
        int pk = 0;
        pk = __builtin_amdgcn_cvt_pk_fp8_f32(v.x, v.y, pk, false);
        pk = __builtin_amdgcn_cvt_pk_fp8_f32(v.z, v.w, pk, true);
        *reinterpret_cast<unsigned int*>(&lds[r * 68 + c * 4]) = (unsigned int)pk;
    }
    __syncthreads();
    #pragma unroll
    for (int p = 0; p < 4; ++p) {
        int sidx = p * 256 + tid;
        int n  = sidx >> 4;      // n within tile (0..63)
        int kg = sidx & 15;      // k group of 4 (orig offset kg*4)
        unsigned int w = 0;
        #pragma unroll
        for (int j = 0; j < 4; ++j)
            w |= (unsigned int)lds[(kg * 4 + j) * 68 + n] << (8 * j);
        const int nn = n0 + n;
        const int o  = kg * 4;                       // orig offset in 64B segment
        const int g  = (o & 31) >> 3;
        const int s  = (o & 7) + ((o >> 5) & 1) * 8;
        const int c  = g ^ ((nn >> 1) & 3);
        *reinterpret_cast<unsigned int*>(
            BT + (long)nn * K + k0 + (c << 4) + s) = w;
    }
}

// ---------------------------------------------------------------------------
// Kernel 3: fp8 GEMM, 256x256 tile, BK=64, 8 waves (2M x 4N), 8-phase-style
// schedule: per K-tile 4 quadrant-phases of 16 MFMA; 1 half-tile staged per
// phase for tile t+2 (3 LDS buffers); counted vmcnt(4) at tile boundaries
// (never 0 in the main loop); raw s_barrier + explicit waits; setprio(1)
// around MFMA clusters.
// ---------------------------------------------------------------------------
__global__ __launch_bounds__(512, 2) void gemm_fp8_kernel(
        const unsigned char* __restrict__ A,   // [M][K] fp8 (permuted layout)
        const unsigned char* __restrict__ BT,  // [N][K] fp8 (permuted layout)
        const float* __restrict__ bias,        // [N]
        float* __restrict__ out,               // [M][N] f32
        int M, int N, int K) {
    constexpr int BM = 256, BN = 256, BK = 64;
    __shared__ unsigned char lds[3][2][BM * BK];   // [buf][A,B][16KB] = 96 KB

    const int tid  = threadIdx.x;
    const int lane = tid & 63;
    const int wid  = tid >> 6;            // 0..7
    const int wm   = wid >> 2;            // 0..1
    const int wn   = wid & 3;             // 0..3

    // XCD-rectangle tile mapping: 8 XCDs as 4x2 over the 16x16 tile grid,
    // each owns a 4x8 rectangle -> ~3MB working set per XCD L2.
    const int bid = blockIdx.x;
    const int xcd = bid & 7, idx = bid >> 3;
    const int tile_m = (xcd & 3) * 4 + (idx & 3);
    const int tile_n = (xcd >> 2) * 8 + (idx >> 2);
    const int m0 = tile_m * BM, n0 = tile_n * BN;

    const int lrow = lane & 15;           // fragment row within 16
    const int kgrp = lane >> 4;           // 0..3, k-group
    const int chunkoff = ((kgrp ^ ((lrow >> 1) & 3)) << 4);

    // staging: one gld16 per thread per half-tile (128 rows x 64B = 8KB)
    const int srow   = tid >> 2;          // 0..127
    const int schunk = (tid & 3) << 4;
    const unsigned char* gA = A  + (long)(m0 + srow) * K + schunk;
    const unsigned char* gB = BT + (long)(n0 + srow) * K + schunk;
    const int ldst = wid * 1024;          // wave-uniform slice in half-tile

    const int aBase = (wm * 128 + lrow) * 64 + chunkoff;
    const int bBase = (wn * 64  + lrow) * 64 + chunkoff;

    f32x4 acc[8][4] = {};   // [ai = qm*4+fi][bj = qn*2+fj]

    const int NT = K / BK;  // 16

#define STAGE(BB, OP, H, TT)                                              \
    gld16((OP ? gB : gA) + (long)(H) * 128 * K + (long)(TT) * BK,         \
          &lds[BB][OP][(H) * 8192 + ldst])

#define PHASE_HEAD()                                                      \
    __builtin_amdgcn_sched_barrier(0);                                    \
    __builtin_amdgcn_s_barrier();                                         \
    asm volatile("s_waitcnt lgkmcnt(0)" ::: "memory");                    \
    __builtin_amdgcn_sched_barrier(0);                                    \
    __builtin_amdgcn_s_setprio(1)

#define PHASE_TAIL()                                                      \
    __builtin_amdgcn_s_setprio(0);                                        \
    __builtin_amdgcn_sched_barrier(0);                                    \
    __builtin_amdgcn_s_barrier()

#define MFMA_Q(AI0, BJ0, BREG)                                            \
    _Pragma("unroll") for (int ks = 0; ks < 2; ++ks)                      \
    _Pragma("unroll") for (int fi = 0; fi < 4; ++fi)                      \
    _Pragma("unroll") for (int fj = 0; fj < 2; ++fj)                      \
        acc[(AI0) + fi][(BJ0) + fj] =                                     \
            __builtin_amdgcn_mfma_f32_16x16x32_fp8_fp8(                   \
                a[fi][ks], BREG[fj][ks], acc[(AI0) + fi][(BJ0) + fj], 0, 0, 0)

    // prologue: stage tiles 0 (buf 0) and 1 (buf 1), keep tile 1 in flight
    STAGE(0, 0, 0, 0); STAGE(0, 0, 1, 0); STAGE(0, 1, 0, 0); STAGE(0, 1, 1, 0);
    STAGE(1, 0, 0, 1); STAGE(1, 0, 1, 1); STAGE(1, 1, 0, 1); STAGE(1, 1, 1, 1);
    asm volatile("s_waitcnt vmcnt(4)" ::: "memory");
    __builtin_amdgcn_sched_barrier(0);
    __builtin_amdgcn_s_barrier();

    int b = 0, b2 = 2;
    for (int t = 0; t < NT; ++t) {
        const unsigned char* sAb = &lds[b][0][0];
        const unsigned char* sBb = &lds[b][1][0];
        const bool st = (t + 2 < NT);
        l2 a[4], br0[2], br1[2];

        // ---- P0: quadrant (0,0); reads A0 + B0; stage (A,h0) of t+2
        #pragma unroll
        for (int f = 0; f < 4; ++f)
            a[f] = *reinterpret_cast<const l2*>(sAb + aBase + f * 1024);
        #pragma unroll
        for (int f = 0; f < 2; ++f)
            br0[f] = *reinterpret_cast<const l2*>(sBb + bBase + f * 1024);
        if (st) { STAGE(b2, 0, 0, t + 2); }
        PHASE_HEAD();
        MFMA_Q(0, 0, br0);
        PHASE_TAIL();

        // ---- P1: quadrant (0,1); reads B1; stage (A,h1)
        #pragma unroll
        for (int f = 0; f < 2; ++f)
            br1[f] = *reinterpret_cast<const l2*>(sBb + bBase + 2048 + f * 1024);
        if (st) { STAGE(b2, 0, 1, t + 2); }
        PHASE_HEAD();
        MFMA_Q(0, 2, br1);
        PHASE_TAIL();

        // ---- P2: quadrant (1,0); reads A1; stage (B,h0)
        #pragma unroll
        for (int f = 0; f < 4; ++f)
            a[f] = *reinterpret_cast<const l2*>(sAb + aBase + 4096 + f * 1024);
        if (st) { STAGE(b2, 1, 0, t + 2); }
        PHASE_HEAD();
        MFMA_Q(4, 0, br0);
        PHASE_TAIL();

        // ---- P3: quadrant (1,1); no reads; stage (B,h1); boundary wait
        if (st) { STAGE(b2, 1, 1, t + 2); }
        __builtin_amdgcn_sched_barrier(0);
        __builtin_amdgcn_s_barrier();
        __builtin_amdgcn_s_setprio(1);
        MFMA_Q(4, 2, br1);
        __builtin_amdgcn_s_setprio(0);
        __builtin_amdgcn_sched_barrier(0);
        if (t < NT - 1) {
            if (st) { asm volatile("s_waitcnt vmcnt(4)" ::: "memory"); }
            else    { asm volatile("s_waitcnt vmcnt(0)" ::: "memory"); }
            __builtin_amdgcn_sched_barrier(0);
            __builtin_amdgcn_s_barrier();
        }
        b  = (b  == 2) ? 0 : b  + 1;
        b2 = (b2 == 2) ? 0 : b2 + 1;
    }

    // epilogue: bias + gelu -> f32
    // C/D layout (16x16, dtype-independent): col = lane&15, row = kgrp*4 + reg
    #pragma unroll
    for (int bj = 0; bj < 4; ++bj) {
        const int col = n0 + wn * 64 + bj * 16 + lrow;
        const float bv = bias[col];
        #pragma unroll
        for (int ai = 0; ai < 8; ++ai) {
            const int rbase = m0 + wm * 128 + ai * 16 + kgrp * 4;
            f32x4 v = acc[ai][bj];
            #pragma unroll
            for (int r = 0; r < 4; ++r) {
                float xv = v[r] + bv;
                out[(long)(rbase + r) * N + col] = gelu_tanh(xv);
            }
        }
    }
#undef STAGE
#undef PHASE_HEAD
#undef PHASE_TAIL
#undef MFMA_Q
}

// ---------------------------------------------------------------------------
extern "C" void kernel_launch(void* const* d_in, const int* in_sizes, int n_in,
                              void* d_out, int out_size, void* d_ws, size_t ws_size,
                              hipStream_t stream) {
    const float* x    = (const float*)d_in[0];   // [tokens][d_in]
    const float* w    = (const float*)d_in[1];   // [d_in][units]
    const float* bias = (const float*)d_in[2];   // [units]
    float* out = (float*)d_out;

    const int units  = in_sizes[2];              // 4096
    const int dmodel = in_sizes[1] / units;      // 1024
    const int tokens = in_sizes[0] / dmodel;     // 4096

    unsigned char* Aq  = (unsigned char*)d_ws;                 // [tokens][dmodel] fp8
    unsigned char* BTq = Aq + (size_t)tokens * dmodel;         // [units][dmodel] fp8

    const int n4a = tokens * dmodel / 4;
    quantA_kernel<<<dim3(n4a / 256), dim3(256), 0, stream>>>(
        x, Aq, n4a, dmodel);

    quantBT_kernel<<<dim3(units / 64, dmodel / 64), dim3(256), 0, stream>>>(
        w, BTq, dmodel, units);

    const int nblocks = (tokens / 256) * (units / 256);
    gemm_fp8_kernel<<<dim3(nblocks), dim3(512), 0, stream>>>(
        Aq, BTq, bias, out, tokens, units, dmodel);
}

// Round 5
// 49.085 us; speedup vs baseline: 1.1445x; 1.1445x over previous
//
#include <hip/hip_runtime.h>
#include <hip/hip_bf16.h>

typedef float f32x4 __attribute__((ext_vector_type(4)));
typedef long  l2    __attribute__((ext_vector_type(2)));

// ---------------------------------------------------------------------------
// async global->LDS, 16B per lane. LDS dest is wave-uniform base (+lane*16).
// ---------------------------------------------------------------------------
__device__ __forceinline__ void gld16(const void* g, void* l) {
    __builtin_amdgcn_global_load_lds(
        (const __attribute__((address_space(1))) void*)g,
        (__attribute__((address_space(3))) void*)l,
        16, 0, 0);
}

// gelu, tanh approximation (matches jax.nn.gelu approximate=True)
__device__ __forceinline__ float gelu_tanh(float x) {
    float u = 0.7978845608028654f * x * (1.0f + 0.044715f * x * x);
    float e = __expf(2.0f * u);
    float t = 1.0f - 2.0f / (e + 1.0f);   // tanh(u)
    return 0.5f * x * (1.0f + t);
}

// ---------------------------------------------------------------------------
// Pre-permuted fp8 storage layout (both A[M][K] and BT[N][K]):
// within each row's 64B k-segment:
//   step 1 (pair ks-halves): chunk g (16B) = orig k-bytes [g*8,+8) ++ [32+g*8,+8)
//   step 2 (bank swizzle):   stored at chunk position c = g ^ ((row>>1)&3)
// GEMM reads one ds_read_b128 per fragment-pair (lo 8B = ks0, hi = ks1),
// conflict-free across the wave. (Verified round 3: SQ_LDS_BANK_CONFLICT = 0.)
// ---------------------------------------------------------------------------

// Kernel 1: quantize x (f32 [M][K]) -> fp8 e4m3, permuted layout
__global__ __launch_bounds__(256) void quantA_kernel(
        const float* __restrict__ in, unsigned char* __restrict__ out,
        int n4, int K) {
    int i = blockIdx.x * 256 + threadIdx.x;
    if (i >= n4) return;
    float4 v = reinterpret_cast<const float4*>(in)[i];
    int pk = 0;
    pk = __builtin_amdgcn_cvt_pk_fp8_f32(v.x, v.y, pk, false);
    pk = __builtin_amdgcn_cvt_pk_fp8_f32(v.z, v.w, pk, true);
    const long k4 = (long)i * 4;
    const int  row = (int)(k4 / K);
    const int  k   = (int)(k4 % K);
    const int  o   = k & 63;
    const int  g   = (o & 31) >> 3;
    const int  s   = (o & 7) + ((o >> 5) & 1) * 8;
    const int  c   = g ^ ((row >> 1) & 3);
    *reinterpret_cast<unsigned int*>(
        out + (long)row * K + (k & ~63) + (c << 4) + s) = (unsigned int)pk;
}

// Kernel 2: quantize + transpose kernel (f32 [K][N]) -> fp8 BT[N][K], permuted
__global__ __launch_bounds__(256) void quantBT_kernel(
        const float* __restrict__ B, unsigned char* __restrict__ BT,
        int K, int N) {
    __shared__ unsigned char lds[64 * 68];    // [k=64][n=64], row stride 68 (pad)
    const int tid = threadIdx.x;
    const int n0 = blockIdx.x * 64;
    const int k0 = blockIdx.y * 64;

    #pragma unroll
    for (int p = 0; p < 4; ++p) {
        int s = p * 256 + tid;
        int r = s >> 4;          // k within tile (0..63)
        int c = s & 15;          // float4 group (covers n = 4c..4c+3)
        float4 v = *reinterpret_cast<const float4*>(
            B + (long)(k0 + r) * N + n0 + c * 4);
        int pk = 0;
        pk = __builtin_amdgcn_cvt_pk_fp8_f32(v.x, v.y, pk, false);
        pk = __builtin_amdgcn_cvt_pk_fp8_f32(v.z, v.w, pk, true);
        *reinterpret_cast<unsigned int*>(&lds[r * 68 + c * 4]) = (unsigned int)pk;
    }
    __syncthreads();
    #pragma unroll
    for (int p = 0; p < 4; ++p) {
        int sidx = p * 256 + tid;
        int n  = sidx >> 4;      // n within tile (0..63)
        int kg = sidx & 15;      // k group of 4 (orig offset kg*4)
        unsigned int w = 0;
        #pragma unroll
        for (int j = 0; j < 4; ++j)
            w |= (unsigned int)lds[(kg * 4 + j) * 68 + n] << (8 * j);
        const int nn = n0 + n;
        const int o  = kg * 4;                       // orig offset in 64B segment
        const int g  = (o & 31) >> 3;
        const int s  = (o & 7) + ((o >> 5) & 1) * 8;
        const int c  = g ^ ((nn >> 1) & 3);
        *reinterpret_cast<unsigned int*>(
            BT + (long)nn * K + k0 + (c << 4) + s) = w;
    }
}

// ---------------------------------------------------------------------------
// Kernel 3: fp8 GEMM, 128x256 tile, BK=64, 8 waves (2M x 4N), 2 blocks/CU.
// Per K-tile: 4 quadrant-phases of 8 MFMA; 3 half-tile stages (A, B0, B1)
// for tile t+2 (3 LDS buffers, 72 KB); counted vmcnt(3) at tile boundaries.
// Epilogue: wave-private LDS transpose -> float4 stores.
// ---------------------------------------------------------------------------
__global__ __launch_bounds__(512, 4) void gemm_fp8_kernel(
        const unsigned char* __restrict__ A,   // [M][K] fp8 (permuted layout)
        const unsigned char* __restrict__ BT,  // [N][K] fp8 (permuted layout)
        const float* __restrict__ bias,        // [N]
        float* __restrict__ out,               // [M][N] f32
        int M, int N, int K) {
    constexpr int BM = 128, BN = 256, BK = 64;
    __shared__ unsigned char lds[3][(BM + BN) * BK];   // 3 x 24 KB = 72 KB

    const int tid  = threadIdx.x;
    const int lane = tid & 63;
    const int wid  = tid >> 6;            // 0..7
    const int wm   = wid >> 2;            // 0..1 (64 rows each)
    const int wn   = wid & 3;             // 0..3 (64 cols each)

    // XCD mapping: 8 XCDs over the 32x16 tile grid, each an 8x8 rectangle
    // (~3 MB working set per XCD L2). Bijective: 512 = 8 * 64.
    const int bid = blockIdx.x;
    const int xcd = bid & 7, idx = bid >> 3;            // idx 0..63
    const int tile_m = (xcd >> 1) * 8 + (idx & 7);      // 0..31
    const int tile_n = (xcd & 1) * 8 + (idx >> 3);      // 0..15
    const int m0 = tile_m * BM, n0 = tile_n * BN;

    const int lrow = lane & 15;           // fragment row within 16
    const int kgrp = lane >> 4;           // 0..3, k-group
    const int chunkoff = ((kgrp ^ ((lrow >> 1) & 3)) << 4);

    // staging: one gld16 per thread per 8KB half (128 rows x 64B)
    const int srow   = tid >> 2;          // 0..127
    const int schunk = (tid & 3) << 4;
    const unsigned char* gA = A  + (long)(m0 + srow) * K + schunk;
    const unsigned char* gB = BT + (long)(n0 + srow) * K + schunk;

    const int aBase = (wm * 64 + lrow) * 64 + chunkoff;            // A rows [0,128)
    const int bBase = 8192 + (wn * 64 + lrow) * 64 + chunkoff;     // B rows [0,256)

    f32x4 acc[4][4] = {};

    const int NT = K / BK;  // 16

#define STAGE_A(BB, TT)                                                   \
    gld16(gA + (long)(TT) * BK, &lds[BB][wid * 1024])
#define STAGE_B(BB, H, TT)                                                \
    gld16(gB + (long)(H) * 128 * K + (long)(TT) * BK,                     \
          &lds[BB][8192 + (H) * 8192 + wid * 1024])

#define PHASE_HEAD()                                                      \
    __builtin_amdgcn_sched_barrier(0);                                    \
    __builtin_amdgcn_s_barrier();                                         \
    asm volatile("s_waitcnt lgkmcnt(0)" ::: "memory");                    \
    __builtin_amdgcn_sched_barrier(0);                                    \
    __builtin_amdgcn_s_setprio(1)

#define PHASE_TAIL()                                                      \
    __builtin_amdgcn_s_setprio(0);                                        \
    __builtin_amdgcn_sched_barrier(0);                                    \
    __builtin_amdgcn_s_barrier()

#define MFMA_Q(AI0, BJ0, AR, BR)                                          \
    _Pragma("unroll") for (int ks = 0; ks < 2; ++ks)                      \
    _Pragma("unroll") for (int fi = 0; fi < 2; ++fi)                      \
    _Pragma("unroll") for (int fj = 0; fj < 2; ++fj)                      \
        acc[(AI0) + fi][(BJ0) + fj] =                                     \
            __builtin_amdgcn_mfma_f32_16x16x32_fp8_fp8(                   \
                AR[fi][ks], BR[fj][ks], acc[(AI0) + fi][(BJ0) + fj], 0, 0, 0)

    // prologue: stage tiles 0 (buf 0) and 1 (buf 1); keep tile 1 in flight
    STAGE_A(0, 0); STAGE_B(0, 0, 0); STAGE_B(0, 1, 0);
    STAGE_A(1, 1); STAGE_B(1, 0, 1); STAGE_B(1, 1, 1);
    asm volatile("s_waitcnt vmcnt(3)" ::: "memory");
    __builtin_amdgcn_sched_barrier(0);
    __builtin_amdgcn_s_barrier();

    int b = 0, b2 = 2;
    for (int t = 0; t < NT; ++t) {
        const unsigned char* sL = &lds[b][0];
        const bool st = (t + 2 < NT);
        l2 a01[2], a23[2], b01[2], b23[2];

        // ---- P0: quadrant (0,0); reads a01 + b01; stage A of t+2
        #pragma unroll
        for (int f = 0; f < 2; ++f) {
            a01[f] = *reinterpret_cast<const l2*>(sL + aBase + f * 1024);
            b01[f] = *reinterpret_cast<const l2*>(sL + bBase + f * 1024);
        }
        if (st) { STAGE_A(b2, t + 2); }
        PHASE_HEAD();
        MFMA_Q(0, 0, a01, b01);
        PHASE_TAIL();

        // ---- P1: quadrant (0,1); reads b23; stage B-h0
        #pragma unroll
        for (int f = 0; f < 2; ++f)
            b23[f] = *reinterpret_cast<const l2*>(sL + bBase + 2048 + f * 1024);
        if (st) { STAGE_B(b2, 0, t + 2); }
        PHASE_HEAD();
        MFMA_Q(0, 2, a01, b23);
        PHASE_TAIL();

        // ---- P2: quadrant (1,0); reads a23; stage B-h1
        #pragma unroll
        for (int f = 0; f < 2; ++f)
            a23[f] = *reinterpret_cast<const l2*>(sL + aBase + 2048 + f * 1024);
        if (st) { STAGE_B(b2, 1, t + 2); }
        PHASE_HEAD();
        MFMA_Q(2, 0, a23, b01);
        PHASE_TAIL();

        // ---- P3: quadrant (1,1); no reads/stages; boundary wait
        __builtin_amdgcn_s_barrier();
        __builtin_amdgcn_s_setprio(1);
        MFMA_Q(2, 2, a23, b23);
        __builtin_amdgcn_s_setprio(0);
        __builtin_amdgcn_sched_barrier(0);
        if (t < NT - 1) {
            if (st) { asm volatile("s_waitcnt vmcnt(3)" ::: "memory"); }
            else    { asm volatile("s_waitcnt vmcnt(0)" ::: "memory"); }
            __builtin_amdgcn_sched_barrier(0);
            __builtin_amdgcn_s_barrier();
        }
        b  = (b  == 2) ? 0 : b  + 1;
        b2 = (b2 == 2) ? 0 : b2 + 1;
    }

    // ------------------------------------------------------------------
    // epilogue: bias + gelu, wave-private LDS transpose, float4 stores.
    // C/D frag layout: col = lrow, row = kgrp*4 + r.
    // ------------------------------------------------------------------
    __syncthreads();   // all LDS traffic of the loop complete; safe to reuse
    float* eplds = reinterpret_cast<float*>(&lds[0][0]) + wid * 1088; // 16x68
    const int  col0   = n0 + wn * 64;
    const long rbase0 = m0 + wm * 64;
    float bv[4];
    #pragma unroll
    for (int bj = 0; bj < 4; ++bj) bv[bj] = bias[col0 + bj * 16 + lrow];

    #pragma unroll
    for (int ai = 0; ai < 4; ++ai) {
        #pragma unroll
        for (int bj = 0; bj < 4; ++bj) {
            #pragma unroll
            for (int r = 0; r < 4; ++r) {
                float xv = acc[ai][bj][r] + bv[bj];
                eplds[(kgrp * 4 + r) * 68 + bj * 16 + lrow] = gelu_tanh(xv);
            }
        }
        #pragma unroll
        for (int s = 0; s < 4; ++s) {
            f32x4 v = *reinterpret_cast<const f32x4*>(
                eplds + (s * 4 + kgrp) * 68 + lrow * 4);
            *reinterpret_cast<f32x4*>(
                out + (rbase0 + ai * 16 + s * 4 + kgrp) * N + col0 + lrow * 4) = v;
        }
    }
#undef STAGE_A
#undef STAGE_B
#undef PHASE_HEAD
#undef PHASE_TAIL
#undef MFMA_Q
}

// ---------------------------------------------------------------------------
extern "C" void kernel_launch(void* const* d_in, const int* in_sizes, int n_in,
                              void* d_out, int out_size, void* d_ws, size_t ws_size,
                              hipStream_t stream) {
    const float* x    = (const float*)d_in[0];   // [tokens][d_in]
    const float* w    = (const float*)d_in[1];   // [d_in][units]
    const float* bias = (const float*)d_in[2];   // [units]
    float* out = (float*)d_out;

    const int units  = in_sizes[2];              // 4096
    const int dmodel = in_sizes[1] / units;      // 1024
    const int tokens = in_sizes[0] / dmodel;     // 4096

    unsigned char* Aq  = (unsigned char*)d_ws;                 // [tokens][dmodel] fp8
    unsigned char* BTq = Aq + (size_t)tokens * dmodel;         // [units][dmodel] fp8

    const int n4a = tokens * dmodel / 4;
    quantA_kernel<<<dim3(n4a / 256), dim3(256), 0, stream>>>(
        x, Aq, n4a, dmodel);

    quantBT_kernel<<<dim3(units / 64, dmodel / 64), dim3(256), 0, stream>>>(
        w, BTq, dmodel, units);

    const int nblocks = (tokens / 128) * (units / 256);
    gemm_fp8_kernel<<<dim3(nblocks), dim3(512), 0, stream>>>(
        Aq, BTq, bias, out, tokens, units, dmodel);
}

// Round 6
// 46.980 us; speedup vs baseline: 1.1958x; 1.0448x over previous
//
#include <hip/hip_runtime.h>
#include <hip/hip_bf16.h>

typedef float f32x4 __attribute__((ext_vector_type(4)));
typedef long  l2    __attribute__((ext_vector_type(2)));

// ---------------------------------------------------------------------------
// async global->LDS, 16B per lane. LDS dest is wave-uniform base (+lane*16).
// ---------------------------------------------------------------------------
__device__ __forceinline__ void gld16(const void* g, void* l) {
    __builtin_amdgcn_global_load_lds(
        (const __attribute__((address_space(1))) void*)g,
        (__attribute__((address_space(3))) void*)l,
        16, 0, 0);
}

// gelu, tanh approximation (matches jax.nn.gelu approximate=True)
__device__ __forceinline__ float gelu_tanh(float x) {
    float u = 0.7978845608028654f * x * (1.0f + 0.044715f * x * x);
    float e = __expf(2.0f * u);
    float t = 1.0f - 2.0f / (e + 1.0f);   // tanh(u)
    return 0.5f * x * (1.0f + t);
}

// ---------------------------------------------------------------------------
// Pre-permuted fp8 storage layout (both A[M][K] and BT[N][K]):
// within each row's 64B k-segment:
//   step 1 (pair ks-halves): chunk g (16B) = orig k-bytes [g*8,+8) ++ [32+g*8,+8)
//   step 2 (bank swizzle):   stored at chunk position c = g ^ ((row>>1)&3)
// GEMM reads one ds_read_b128 per fragment-pair (lo 8B = ks0, hi = ks1),
// conflict-free across the wave. (Verified round 3: SQ_LDS_BANK_CONFLICT = 0.)
// ---------------------------------------------------------------------------

// Fused quantize kernel: blocks [0, nA) do x -> Aq; blocks [nA, nA+nB) do
// w -> BTq (transpose via LDS). Single launch so the two halves overlap.
__global__ __launch_bounds__(256) void quant_fused_kernel(
        const float* __restrict__ x,  unsigned char* __restrict__ Aq,
        const float* __restrict__ w,  unsigned char* __restrict__ BTq,
        int nA, int K, int N) {
    __shared__ unsigned char lds[64 * 68];
    const int tid = threadIdx.x;

    if (blockIdx.x < nA) {
        // ---- quantA: 256 threads x float4
        int i = blockIdx.x * 256 + tid;
        float4 v = reinterpret_cast<const float4*>(x)[i];
        int pk = 0;
        pk = __builtin_amdgcn_cvt_pk_fp8_f32(v.x, v.y, pk, false);
        pk = __builtin_amdgcn_cvt_pk_fp8_f32(v.z, v.w, pk, true);
        const long k4 = (long)i * 4;
        const int  row = (int)(k4 / K);
        const int  k   = (int)(k4 % K);
        const int  o   = k & 63;
        const int  g   = (o & 31) >> 3;
        const int  s   = (o & 7) + ((o >> 5) & 1) * 8;
        const int  c   = g ^ ((row >> 1) & 3);
        *reinterpret_cast<unsigned int*>(
            Aq + (long)row * K + (k & ~63) + (c << 4) + s) = (unsigned int)pk;
        return;
    }

    // ---- quantBT: 64x64 tile transpose through LDS
    const int bid = blockIdx.x - nA;
    const int n0 = (bid & (N / 64 - 1)) * 64;
    const int k0 = (bid / (N / 64)) * 64;

    #pragma unroll
    for (int p = 0; p < 4; ++p) {
        int s = p * 256 + tid;
        int r = s >> 4;          // k within tile (0..63)
        int c = s & 15;          // float4 group (covers n = 4c..4c+3)
        float4 v = *reinterpret_cast<const float4*>(
            w + (long)(k0 + r) * N + n0 + c * 4);
        int pk = 0;
        pk = __builtin_amdgcn_cvt_pk_fp8_f32(v.x, v.y, pk, false);
        pk = __builtin_amdgcn_cvt_pk_fp8_f32(v.z, v.w, pk, true);
        *reinterpret_cast<unsigned int*>(&lds[r * 68 + c * 4]) = (unsigned int)pk;
    }
    __syncthreads();
    #pragma unroll
    for (int p = 0; p < 4; ++p) {
        int sidx = p * 256 + tid;
        int n  = sidx >> 4;      // n within tile (0..63)
        int kg = sidx & 15;      // k group of 4 (orig offset kg*4)
        unsigned int wv = 0;
        #pragma unroll
        for (int j = 0; j < 4; ++j)
            wv |= (unsigned int)lds[(kg * 4 + j) * 68 + n] << (8 * j);
        const int nn = n0 + n;
        const int o  = kg * 4;
        const int g  = (o & 31) >> 3;
        const int s  = (o & 7) + ((o >> 5) & 1) * 8;
        const int c  = g ^ ((nn >> 1) & 3);
        *reinterpret_cast<unsigned int*>(
            BTq + (long)nn * K + k0 + (c << 4) + s) = wv;
    }
}

// ---------------------------------------------------------------------------
// fp8 GEMM, 128x256 tile, BK=64, 8 waves (2M x 4N), 2 blocks/CU.
// Per K-tile: 2 phases of 16 MFMA (3 barriers/tile); 3 half-tile stages
// (A, B0 | B1) for tile t+2 across 3 LDS buffers (72 KB); counted vmcnt(3)
// at tile boundaries (never 0 in the main loop).
// Epilogue: wave-private LDS transpose -> nontemporal float4 stores.
// ---------------------------------------------------------------------------
__global__ __launch_bounds__(512, 4) void gemm_fp8_kernel(
        const unsigned char* __restrict__ A,   // [M][K] fp8 (permuted layout)
        const unsigned char* __restrict__ BT,  // [N][K] fp8 (permuted layout)
        const float* __restrict__ bias,        // [N]
        float* __restrict__ out,               // [M][N] f32
        int M, int N, int K) {
    constexpr int BM = 128, BN = 256, BK = 64;
    __shared__ unsigned char lds[3][(BM + BN) * BK];   // 3 x 24 KB = 72 KB

    const int tid  = threadIdx.x;
    const int lane = tid & 63;
    const int wid  = tid >> 6;            // 0..7
    const int wm   = wid >> 2;            // 0..1 (64 rows each)
    const int wn   = wid & 3;             // 0..3 (64 cols each)

    // XCD mapping: 8 XCDs over the 32x16 tile grid, each an 8x8 rectangle
    // (~3 MB working set per XCD L2). Bijective: 512 = 8 * 64.
    const int bid = blockIdx.x;
    const int xcd = bid & 7, idx = bid >> 3;            // idx 0..63
    const int tile_m = (xcd >> 1) * 8 + (idx & 7);      // 0..31
    const int tile_n = (xcd & 1) * 8 + (idx >> 3);      // 0..15
    const int m0 = tile_m * BM, n0 = tile_n * BN;

    const int lrow = lane & 15;           // fragment row within 16
    const int kgrp = lane >> 4;           // 0..3, k-group
    const int chunkoff = ((kgrp ^ ((lrow >> 1) & 3)) << 4);

    // staging: one gld16 per thread per 8KB half (128 rows x 64B)
    const int srow   = tid >> 2;          // 0..127
    const int schunk = (tid & 3) << 4;
    const unsigned char* gA = A  + (long)(m0 + srow) * K + schunk;
    const unsigned char* gB = BT + (long)(n0 + srow) * K + schunk;

    const int aBase = (wm * 64 + lrow) * 64 + chunkoff;            // A rows [0,128)
    const int bBase = 8192 + (wn * 64 + lrow) * 64 + chunkoff;     // B rows [0,256)

    f32x4 acc[4][4] = {};

    const int NT = K / BK;  // 16

#define STAGE_A(BB, TT)                                                   \
    gld16(gA + (long)(TT) * BK, &lds[BB][wid * 1024])
#define STAGE_B(BB, H, TT)                                                \
    gld16(gB + (long)(H) * 128 * K + (long)(TT) * BK,                     \
          &lds[BB][8192 + (H) * 8192 + wid * 1024])

#define MFMA_Q(AI0, BJ0, AR, BR)                                          \
    _Pragma("unroll") for (int ks = 0; ks < 2; ++ks)                      \
    _Pragma("unroll") for (int fi = 0; fi < 2; ++fi)                      \
    _Pragma("unroll") for (int fj = 0; fj < 2; ++fj)                      \
        acc[(AI0) + fi][(BJ0) + fj] =                                     \
            __builtin_amdgcn_mfma_f32_16x16x32_fp8_fp8(                   \
                AR[fi][ks], BR[fj][ks], acc[(AI0) + fi][(BJ0) + fj], 0, 0, 0)

    // prologue: stage tiles 0 (buf 0) and 1 (buf 1); keep tile 1 in flight
    STAGE_A(0, 0); STAGE_B(0, 0, 0); STAGE_B(0, 1, 0);
    STAGE_A(1, 1); STAGE_B(1, 0, 1); STAGE_B(1, 1, 1);
    asm volatile("s_waitcnt vmcnt(3)" ::: "memory");
    __builtin_amdgcn_s_barrier();

    int b = 0, b2 = 2;
    for (int t = 0; t < NT; ++t) {
        const unsigned char* sL = &lds[b][0];
        const bool st = (t + 2 < NT);
        l2 a01[2], a23[2], b01[2], b23[2];

        // ---- phase 0: stages A,B0 of t+2; reads a01,b01,b23; MFMA rows 0-1
        if (st) { STAGE_A(b2, t + 2); STAGE_B(b2, 0, t + 2); }
        #pragma unroll
        for (int f = 0; f < 2; ++f) {
            a01[f] = *reinterpret_cast<const l2*>(sL + aBase + f * 1024);
            b01[f] = *reinterpret_cast<const l2*>(sL + bBase + f * 1024);
            b23[f] = *reinterpret_cast<const l2*>(sL + bBase + 2048 + f * 1024);
        }
        __builtin_amdgcn_s_barrier();
        asm volatile("s_waitcnt lgkmcnt(0)" ::: "memory");
        __builtin_amdgcn_sched_barrier(0);
        __builtin_amdgcn_s_setprio(1);
        MFMA_Q(0, 0, a01, b01);
        MFMA_Q(0, 2, a01, b23);
        __builtin_amdgcn_s_setprio(0);

        // ---- phase 1: stage B1 of t+2; reads a23; MFMA rows 2-3
        if (st) { STAGE_B(b2, 1, t + 2); }
        #pragma unroll
        for (int f = 0; f < 2; ++f)
            a23[f] = *reinterpret_cast<const l2*>(sL + aBase + 2048 + f * 1024);
        __builtin_amdgcn_s_barrier();
        asm volatile("s_waitcnt lgkmcnt(0)" ::: "memory");
        __builtin_amdgcn_sched_barrier(0);
        __builtin_amdgcn_s_setprio(1);
        MFMA_Q(2, 0, a23, b01);
        MFMA_Q(2, 2, a23, b23);
        __builtin_amdgcn_s_setprio(0);
        __builtin_amdgcn_sched_barrier(0);

        // ---- tile boundary: counted wait, one barrier
        if (t < NT - 1) {
            if (st) { asm volatile("s_waitcnt vmcnt(3)" ::: "memory"); }
            else    { asm volatile("s_waitcnt vmcnt(0)" ::: "memory"); }
            __builtin_amdgcn_sched_barrier(0);
            __builtin_amdgcn_s_barrier();
        }
        b  = (b  == 2) ? 0 : b  + 1;
        b2 = (b2 == 2) ? 0 : b2 + 1;
    }

    // ------------------------------------------------------------------
    // epilogue: bias + gelu, wave-private LDS transpose, nt float4 stores.
    // C/D frag layout: col = lrow, row = kgrp*4 + r.
    // ------------------------------------------------------------------
    __syncthreads();   // all LDS traffic of the loop complete; safe to reuse
    float* eplds = reinterpret_cast<float*>(&lds[0][0]) + wid * 1088; // 16x68
    const int  col0   = n0 + wn * 64;
    const long rbase0 = m0 + wm * 64;
    float bv[4];
    #pragma unroll
    for (int bj = 0; bj < 4; ++bj) bv[bj] = bias[col0 + bj * 16 + lrow];

    #pragma unroll
    for (int ai = 0; ai < 4; ++ai) {
        #pragma unroll
        for (int bj = 0; bj < 4; ++bj) {
            #pragma unroll
            for (int r = 0; r < 4; ++r) {
                float xv = acc[ai][bj][r] + bv[bj];
                eplds[(kgrp * 4 + r) * 68 + bj * 16 + lrow] = gelu_tanh(xv);
            }
        }
        #pragma unroll
        for (int s = 0; s < 4; ++s) {
            f32x4 v = *reinterpret_cast<const f32x4*>(
                eplds + (s * 4 + kgrp) * 68 + lrow * 4);
            __builtin_nontemporal_store(v, reinterpret_cast<f32x4*>(
                out + (rbase0 + ai * 16 + s * 4 + kgrp) * N + col0 + lrow * 4));
        }
    }
#undef STAGE_A
#undef STAGE_B
#undef MFMA_Q
}

// ---------------------------------------------------------------------------
extern "C" void kernel_launch(void* const* d_in, const int* in_sizes, int n_in,
                              void* d_out, int out_size, void* d_ws, size_t ws_size,
                              hipStream_t stream) {
    const float* x    = (const float*)d_in[0];   // [tokens][d_in]
    const float* w    = (const float*)d_in[1];   // [d_in][units]
    const float* bias = (const float*)d_in[2];   // [units]
    float* out = (float*)d_out;

    const int units  = in_sizes[2];              // 4096
    const int dmodel = in_sizes[1] / units;      // 1024
    const int tokens = in_sizes[0] / dmodel;     // 4096

    unsigned char* Aq  = (unsigned char*)d_ws;                 // [tokens][dmodel] fp8
    unsigned char* BTq = Aq + (size_t)tokens * dmodel;         // [units][dmodel] fp8

    const int nA = tokens * dmodel / 4 / 256;                  // 4096 blocks
    const int nB = (units / 64) * (dmodel / 64);               // 1024 blocks
    quant_fused_kernel<<<dim3(nA + nB), dim3(256), 0, stream>>>(
        x, Aq, w, BTq, nA, dmodel, units);

    const int nblocks = (tokens / 128) * (units / 256);
    gemm_fp8_kernel<<<dim3(nblocks), dim3(512), 0, stream>>>(
        Aq, BTq, bias, out, tokens, units, dmodel);
}